// Round 2
// baseline (130.671 us; speedup 1.0000x reference)
//
#include <hip/hip_runtime.h>

#define NPIX (512*512)
#define CCH 32
#define KCL 16
#define TPIX 4096
#define BLKT 512
#define STEPS (TPIX/256)
#define WS_STRIDE 544   // per-image floats: cnt[16], sq[16], sums[16][32]

// ---------------- accumulate kernel ----------------
// grid: 512 blocks = 8 images x 64 tiles; block: 512 threads = 8 waves
// wave w handles channels {w, w+8, w+16, w+24} for the whole tile.
// __launch_bounds__(512,4): cap VGPR at 128 -> 4 waves/SIMD, 2 blocks/CU.

__device__ __forceinline__ void run_tile(const float* __restrict__ f0,
    const float* __restrict__ f1, const float* __restrict__ f2,
    const float* __restrict__ f3, const unsigned char* slab, int lane,
    float acc[4][KCL], float* sqa)
{
  #pragma unroll 2
  for (int s = 0; s < STEPS; ++s) {
    const int p = s * 256 + lane * 4;
    const unsigned int labw = *reinterpret_cast<const unsigned int*>(slab + p);
    const float4 a0 = *reinterpret_cast<const float4*>(f0 + p);
    const float4 a1 = *reinterpret_cast<const float4*>(f1 + p);
    const float4 a2 = *reinterpret_cast<const float4*>(f2 + p);
    const float4 a3 = *reinterpret_cast<const float4*>(f3 + p);
    const float va0[4] = {a0.x, a0.y, a0.z, a0.w};
    const float va1[4] = {a1.x, a1.y, a1.z, a1.w};
    const float va2[4] = {a2.x, a2.y, a2.z, a2.w};
    const float va3[4] = {a3.x, a3.y, a3.z, a3.w};
    #pragma unroll
    for (int px = 0; px < 4; ++px) {
      const int lab = (int)((labw >> (8 * px)) & 0xFF);
      const float v0 = va0[px], v1 = va1[px], v2 = va2[px], v3 = va3[px];
      float sq = v0 * v0;
      sq = fmaf(v1, v1, sq);
      sq = fmaf(v2, v2, sq);
      sq = fmaf(v3, v3, sq);
      #pragma unroll
      for (int k = 0; k < KCL; ++k) {
        const float m = (lab == k) ? 1.0f : 0.0f;
        acc[0][k] = fmaf(m, v0, acc[0][k]);
        acc[1][k] = fmaf(m, v1, acc[1][k]);
        acc[2][k] = fmaf(m, v2, acc[2][k]);
        acc[3][k] = fmaf(m, v3, acc[3][k]);
        sqa[k]    = fmaf(m, sq, sqa[k]);
      }
    }
  }
}

// reduce-scatter one level: keep lo/hi half by lane bit, exchange the other.
#define RS_LEVEL(ARR, HALF, MASK) { \
    const bool hi = (lane & (MASK)) != 0; \
    _Pragma("unroll") \
    for (int j = 0; j < (HALF); ++j) { \
      float send = hi ? ARR[j] : ARR[j + (HALF)]; \
      float recv = __shfl_xor(send, (MASK), 64); \
      ARR[j] = (hi ? ARR[j + (HALF)] : ARR[j]) + recv; \
    } }

__global__ void __launch_bounds__(BLKT, 4)
cl_accum_kernel(const float* __restrict__ feats, const int* __restrict__ labs,
                float* __restrict__ ws)
{
  const int b    = blockIdx.x >> 6;     // image
  const int tile = blockIdx.x & 63;
  const int tid  = threadIdx.x;
  const int wave = tid >> 6;
  const int lane = tid & 63;
  const int px0  = tile * TPIX;

  __shared__ unsigned char slab[TPIX];
  const int* lb = labs + b * NPIX + px0;
  #pragma unroll
  for (int i = 0; i < TPIX / BLKT; ++i)
    slab[tid + i * BLKT] = (unsigned char)lb[tid + i * BLKT];
  __syncthreads();

  const float* fbase = feats + ((long long)b * CCH) * NPIX + px0;
  const float* f0 = fbase + (long long)(wave     ) * NPIX;
  const float* f1 = fbase + (long long)(wave +  8) * NPIX;
  const float* f2 = fbase + (long long)(wave + 16) * NPIX;
  const float* f3 = fbase + (long long)(wave + 24) * NPIX;

  float acc[4][KCL];
  float sqa[KCL];
  #pragma unroll
  for (int ch = 0; ch < 4; ++ch)
    #pragma unroll
    for (int k = 0; k < KCL; ++k) acc[ch][k] = 0.f;
  #pragma unroll
  for (int k = 0; k < KCL; ++k) sqa[k] = 0.f;

  run_tile(f0, f1, f2, f3, slab, lane, acc, sqa);

  // ---- per-thread label histogram (post-loop; keeps cnt out of hot regs) ----
  float cnt[KCL];
  #pragma unroll
  for (int k = 0; k < KCL; ++k) cnt[k] = 0.f;
  {
    const unsigned int w0 = *reinterpret_cast<const unsigned int*>(slab + tid * 8);
    const unsigned int w1 = *reinterpret_cast<const unsigned int*>(slab + tid * 8 + 4);
    #pragma unroll
    for (int j = 0; j < 4; ++j) {
      const int l0 = (int)((w0 >> (8 * j)) & 0xFF);
      const int l1 = (int)((w1 >> (8 * j)) & 0xFF);
      #pragma unroll
      for (int k = 0; k < KCL; ++k) {
        cnt[k] += (l0 == k) ? 1.0f : 0.0f;
        cnt[k] += (l1 == k) ? 1.0f : 0.0f;
      }
    }
  }

  // ---- sums: 64 values -> reduce-scatter, lane l ends with value brev6(l) ----
  float a[64];
  #pragma unroll
  for (int ch = 0; ch < 4; ++ch)
    #pragma unroll
    for (int k = 0; k < KCL; ++k) a[ch * 16 + k] = acc[ch][k];

  RS_LEVEL(a, 32,  1)
  RS_LEVEL(a, 16,  2)
  RS_LEVEL(a,  8,  4)
  RS_LEVEL(a,  4,  8)
  RS_LEVEL(a,  2, 16)
  RS_LEVEL(a,  1, 32)

  {
    const int v6  = (int)(__brev((unsigned)lane) >> 26);  // value index
    const int chl = v6 >> 4, k = v6 & 15;
    const int c   = wave + chl * 8;
    atomicAdd(&ws[b * WS_STRIDE + 32 + k * 32 + c], a[0]);
  }

  // ---- sq(16) + cnt(16): 32 values over 5 levels, then fold across halves ----
  float bb[32];
  #pragma unroll
  for (int k = 0; k < KCL; ++k) { bb[k] = sqa[k]; bb[16 + k] = cnt[k]; }
  RS_LEVEL(bb, 16,  1)
  RS_LEVEL(bb,  8,  2)
  RS_LEVEL(bb,  4,  4)
  RS_LEVEL(bb,  2,  8)
  RS_LEVEL(bb,  1, 16)
  bb[0] += __shfl_xor(bb[0], 32, 64);
  if (lane < 32) {
    const int v5 = (int)(__brev((unsigned)(lane)) >> 27);
    if (v5 < 16) atomicAdd(&ws[b * WS_STRIDE + 16 + v5], bb[0]);   // sq
    else         atomicAdd(&ws[b * WS_STRIDE + (v5 - 16)], bb[0]); // cnt
  }
}

// ---------------- finalize kernel ----------------
// 1 block, 512 threads; wave w handles image w.
__global__ void __launch_bounds__(512)
cl_finalize_kernel(const float* __restrict__ ws, float* __restrict__ out)
{
  __shared__ float smean[8][KCL][33];   // padded stride 33 vs bank conflicts
  __shared__ float slossb[8];
  const int tid  = threadIdx.x;
  const int w    = tid >> 6;
  const int lane = tid & 63;
  const float* base = ws + w * WS_STRIDE;

  // means + ||m||^2 partials (lane covers 8 of the 512 (k,c) entries)
  float m2part = 0.f;
  #pragma unroll
  for (int j = 0; j < 8; ++j) {
    const int idx = lane * 8 + j;
    const int k = idx >> 5, c = idx & 31;
    const float m = base[32 + k * 32 + c] / base[k];
    smean[w][k][c] = m;
    m2part = fmaf(m, m, m2part);
  }
  float varp = -m2part;
  if (lane < 16) varp += base[16 + lane] / base[lane];   // Sq_k / cnt_k
  #pragma unroll
  for (int mk = 1; mk < 64; mk <<= 1) varp += __shfl_xor(varp, mk, 64);
  // varp == var_loss on all lanes

  __syncthreads();

  // reg term: 4 lanes per cluster k
  const int kk = lane >> 2, q = lane & 3;
  float n2 = 0.f;
  #pragma unroll
  for (int j = 0; j < 8; ++j) {
    const float m = smean[w][kk][q * 8 + j];
    n2 = fmaf(m, m, n2);
  }
  n2 += __shfl_xor(n2, 1, 64);
  n2 += __shfl_xor(n2, 2, 64);
  float regp = (q == 0) ? sqrtf(n2) : 0.f;
  #pragma unroll
  for (int mk = 1; mk < 64; mk <<= 1) regp += __shfl_xor(regp, mk, 64);
  // regp == sum_k ||m_k|| on all lanes

  // pairwise hinge over 120 pairs
  float hing = 0.f;
  for (int p = lane; p < 120; p += 64) {
    int i = 0, rem = p;
    while (rem >= 15 - i) { rem -= 15 - i; ++i; }
    const int jj = i + 1 + rem;
    float d2 = 0.f;
    #pragma unroll
    for (int c = 0; c < 32; ++c) {
      const float d = smean[w][i][c] - smean[w][jj][c];
      d2 = fmaf(d, d, d2);
    }
    const float h = fmaxf(5.0f - sqrtf(d2), 0.f);   // 2*DD = 5.0
    hing = fmaf(h, h, hing);
  }
  #pragma unroll
  for (int mk = 1; mk < 64; mk <<= 1) hing += __shfl_xor(hing, mk, 64);

  if (lane == 0)
    slossb[w] = (varp + hing * (1.0f / 15.0f) + 0.005f * regp) * (1.0f / 16.0f);
  __syncthreads();
  if (tid == 0) {
    float t = 0.f;
    #pragma unroll
    for (int i = 0; i < 8; ++i) t += slossb[i];
    out[0] = t * (1.0f / 9.0f);
  }
}

extern "C" void kernel_launch(void* const* d_in, const int* in_sizes, int n_in,
                              void* d_out, int out_size, void* d_ws, size_t ws_size,
                              hipStream_t stream)
{
  const float* feats = (const float*)d_in[0];
  const int*   labs  = (const int*)d_in[1];
  float* out = (float*)d_out;
  float* ws  = (float*)d_ws;

  hipMemsetAsync(d_ws, 0, 8 * WS_STRIDE * sizeof(float), stream);
  hipLaunchKernelGGL(cl_accum_kernel, dim3(512), dim3(BLKT), 0, stream,
                     feats, labs, ws);
  hipLaunchKernelGGL(cl_finalize_kernel, dim3(1), dim3(512), 0, stream,
                     ws, out);
}

// Round 3
// 74.423 us; speedup vs baseline: 1.7558x; 1.7558x over previous
//
#include <hip/hip_runtime.h>

#define NPIX (512*512)
#define CCH 32
#define KCL 16
#define TPIX 4096
#define BLKT 512
#define STEPS (TPIX/256)
#define WS_STRIDE 544   // per-image floats: [0..15]=cnt, [16]=wsum, [32..543]=sums[16][32]

// reduce-scatter one level: keep lo/hi half by lane bit, exchange the other.
#define RS_LEVEL(ARR, HALF, MASK) { \
    const bool hi = (lane & (MASK)) != 0; \
    _Pragma("unroll") \
    for (int j = 0; j < (HALF); ++j) { \
      float send = hi ? ARR[j] : ARR[j + (HALF)]; \
      float recv = __shfl_xor(send, (MASK), 64); \
      ARR[j] = (hi ? ARR[j + (HALF)] : ARR[j]) + recv; \
    } }

// ---------------- label histogram kernel ----------------
// 128 blocks = 8 images x 16 segments; 512 threads; 32 labels/thread.
__global__ void __launch_bounds__(512)
cl_hist_kernel(const int* __restrict__ labs, float* __restrict__ ws)
{
  const int b    = blockIdx.x >> 4;
  const int seg  = blockIdx.x & 15;
  const int tid  = threadIdx.x;
  const int lane = tid & 63;
  const int* base = labs + b * NPIX + seg * (NPIX / 16);

  float c[KCL];
  #pragma unroll
  for (int k = 0; k < KCL; ++k) c[k] = 0.f;
  #pragma unroll 4
  for (int i = 0; i < 32; ++i) {
    const int v = base[tid + i * 512];
    #pragma unroll
    for (int k = 0; k < KCL; ++k) c[k] += (v == k) ? 1.0f : 0.0f;
  }
  RS_LEVEL(c, 8, 1)
  RS_LEVEL(c, 4, 2)
  RS_LEVEL(c, 2, 4)
  RS_LEVEL(c, 1, 8)
  c[0] += __shfl_xor(c[0], 16, 64);
  c[0] += __shfl_xor(c[0], 32, 64);
  if (lane < KCL) {
    const int v4 = (int)(__brev((unsigned)lane) >> 28);
    atomicAdd(&ws[b * WS_STRIDE + v4], c[0]);
  }
}

// ---------------- accumulate kernel ----------------
// grid: 512 blocks = 8 images x 64 tiles; block: 512 threads = 8 waves
// wave w handles channels {w, w+8, w+16, w+24}. 4 waves/SIMD (cap 128 VGPR);
// live set ~115 after removing sqa/cnt from the hot loop.
__global__ void __launch_bounds__(BLKT, 4)
cl_accum_kernel(const float* __restrict__ feats, const int* __restrict__ labs,
                float* __restrict__ ws)
{
  const int b    = blockIdx.x >> 6;
  const int tile = blockIdx.x & 63;
  const int tid  = threadIdx.x;
  const int wave = tid >> 6;
  const int lane = tid & 63;
  const int px0  = tile * TPIX;

  __shared__ unsigned char slab[TPIX];
  __shared__ float swei[TPIX];
  const int* lb = labs + b * NPIX + px0;
  const float* cntp = ws + b * WS_STRIDE;
  #pragma unroll
  for (int i = 0; i < TPIX / BLKT; ++i) {
    const int v = lb[tid + i * BLKT];
    slab[tid + i * BLKT] = (unsigned char)v;
    swei[tid + i * BLKT] = 1.0f / cntp[v];
  }
  __syncthreads();

  const float* fbase = feats + ((long long)b * CCH) * NPIX + px0;
  const float* f0 = fbase + (long long)(wave     ) * NPIX;
  const float* f1 = fbase + (long long)(wave +  8) * NPIX;
  const float* f2 = fbase + (long long)(wave + 16) * NPIX;
  const float* f3 = fbase + (long long)(wave + 24) * NPIX;

  float acc[4][KCL];
  #pragma unroll
  for (int ch = 0; ch < 4; ++ch)
    #pragma unroll
    for (int k = 0; k < KCL; ++k) acc[ch][k] = 0.f;
  float wsum = 0.f;

  #pragma unroll 2
  for (int s = 0; s < STEPS; ++s) {
    const int p = s * 256 + lane * 4;
    const unsigned int labw = *reinterpret_cast<const unsigned int*>(slab + p);
    const float4 w4 = *reinterpret_cast<const float4*>(swei + p);
    const float4 a0 = *reinterpret_cast<const float4*>(f0 + p);
    const float4 a1 = *reinterpret_cast<const float4*>(f1 + p);
    const float4 a2 = *reinterpret_cast<const float4*>(f2 + p);
    const float4 a3 = *reinterpret_cast<const float4*>(f3 + p);
    const float va0[4] = {a0.x, a0.y, a0.z, a0.w};
    const float va1[4] = {a1.x, a1.y, a1.z, a1.w};
    const float va2[4] = {a2.x, a2.y, a2.z, a2.w};
    const float va3[4] = {a3.x, a3.y, a3.z, a3.w};
    const float vw[4]  = {w4.x, w4.y, w4.z, w4.w};
    #pragma unroll
    for (int px = 0; px < 4; ++px) {
      const int lab = (int)((labw >> (8 * px)) & 0xFF);
      const float v0 = va0[px], v1 = va1[px], v2 = va2[px], v3 = va3[px];
      float sq = v0 * v0;
      sq = fmaf(v1, v1, sq);
      sq = fmaf(v2, v2, sq);
      sq = fmaf(v3, v3, sq);
      wsum = fmaf(vw[px], sq, wsum);
      #pragma unroll
      for (int k = 0; k < KCL; ++k) {
        const float m = (lab == k) ? 1.0f : 0.0f;
        acc[0][k] = fmaf(m, v0, acc[0][k]);
        acc[1][k] = fmaf(m, v1, acc[1][k]);
        acc[2][k] = fmaf(m, v2, acc[2][k]);
        acc[3][k] = fmaf(m, v3, acc[3][k]);
      }
    }
  }

  // ---- sums: 64 values -> reduce-scatter, lane l ends with value brev6(l) ----
  float a[64];
  #pragma unroll
  for (int ch = 0; ch < 4; ++ch)
    #pragma unroll
    for (int k = 0; k < KCL; ++k) a[ch * 16 + k] = acc[ch][k];

  RS_LEVEL(a, 32,  1)
  RS_LEVEL(a, 16,  2)
  RS_LEVEL(a,  8,  4)
  RS_LEVEL(a,  4,  8)
  RS_LEVEL(a,  2, 16)
  RS_LEVEL(a,  1, 32)

  {
    const int v6  = (int)(__brev((unsigned)lane) >> 26);  // value index
    const int chl = v6 >> 4, k = v6 & 15;
    const int c   = wave + chl * 8;
    atomicAdd(&ws[b * WS_STRIDE + 32 + k * 32 + c], a[0]);
  }

  // ---- wsum: plain wave reduce, one atomic per wave ----
  #pragma unroll
  for (int mk = 1; mk < 64; mk <<= 1) wsum += __shfl_xor(wsum, mk, 64);
  if (lane == 0) atomicAdd(&ws[b * WS_STRIDE + 16], wsum);
}

// ---------------- finalize kernel ----------------
// 1 block, 512 threads; wave w handles image w.
__global__ void __launch_bounds__(512)
cl_finalize_kernel(const float* __restrict__ ws, float* __restrict__ out)
{
  __shared__ float smean[8][KCL][33];   // padded stride 33 vs bank conflicts
  __shared__ float slossb[8];
  const int tid  = threadIdx.x;
  const int w    = tid >> 6;
  const int lane = tid & 63;
  const float* base = ws + w * WS_STRIDE;

  // means + ||m||^2 partials (lane covers 8 of the 512 (k,c) entries)
  float m2part = 0.f;
  #pragma unroll
  for (int j = 0; j < 8; ++j) {
    const int idx = lane * 8 + j;
    const int k = idx >> 5, c = idx & 31;
    const float m = base[32 + k * 32 + c] / base[k];
    smean[w][k][c] = m;
    m2part = fmaf(m, m, m2part);
  }
  float varp = -m2part;
  if (lane == 0) varp += base[16];   // wsum = sum_k Sq_k / cnt_k
  #pragma unroll
  for (int mk = 1; mk < 64; mk <<= 1) varp += __shfl_xor(varp, mk, 64);
  // varp == var_loss on all lanes

  __syncthreads();

  // reg term: 4 lanes per cluster k
  const int kk = lane >> 2, q = lane & 3;
  float n2 = 0.f;
  #pragma unroll
  for (int j = 0; j < 8; ++j) {
    const float m = smean[w][kk][q * 8 + j];
    n2 = fmaf(m, m, n2);
  }
  n2 += __shfl_xor(n2, 1, 64);
  n2 += __shfl_xor(n2, 2, 64);
  float regp = (q == 0) ? sqrtf(n2) : 0.f;
  #pragma unroll
  for (int mk = 1; mk < 64; mk <<= 1) regp += __shfl_xor(regp, mk, 64);
  // regp == sum_k ||m_k|| on all lanes

  // pairwise hinge over 120 pairs
  float hing = 0.f;
  for (int p = lane; p < 120; p += 64) {
    int i = 0, rem = p;
    while (rem >= 15 - i) { rem -= 15 - i; ++i; }
    const int jj = i + 1 + rem;
    float d2 = 0.f;
    #pragma unroll
    for (int c = 0; c < 32; ++c) {
      const float d = smean[w][i][c] - smean[w][jj][c];
      d2 = fmaf(d, d, d2);
    }
    const float h = fmaxf(5.0f - sqrtf(d2), 0.f);   // 2*DD = 5.0
    hing = fmaf(h, h, hing);
  }
  #pragma unroll
  for (int mk = 1; mk < 64; mk <<= 1) hing += __shfl_xor(hing, mk, 64);

  if (lane == 0)
    slossb[w] = (varp + hing * (1.0f / 15.0f) + 0.005f * regp) * (1.0f / 16.0f);
  __syncthreads();
  if (tid == 0) {
    float t = 0.f;
    #pragma unroll
    for (int i = 0; i < 8; ++i) t += slossb[i];
    out[0] = t * (1.0f / 9.0f);
  }
}

extern "C" void kernel_launch(void* const* d_in, const int* in_sizes, int n_in,
                              void* d_out, int out_size, void* d_ws, size_t ws_size,
                              hipStream_t stream)
{
  const float* feats = (const float*)d_in[0];
  const int*   labs  = (const int*)d_in[1];
  float* out = (float*)d_out;
  float* ws  = (float*)d_ws;

  hipMemsetAsync(d_ws, 0, 8 * WS_STRIDE * sizeof(float), stream);
  hipLaunchKernelGGL(cl_hist_kernel, dim3(128), dim3(512), 0, stream,
                     labs, ws);
  hipLaunchKernelGGL(cl_accum_kernel, dim3(512), dim3(BLKT), 0, stream,
                     feats, labs, ws);
  hipLaunchKernelGGL(cl_finalize_kernel, dim3(1), dim3(512), 0, stream,
                     ws, out);
}